// Round 3
// baseline (581.992 us; speedup 1.0000x reference)
//
#include <hip/hip_runtime.h>
#include <stdint.h>

// B=8, N=4096, C=768, H=8, hd=96. bf16 MFMA path.
// Algebraic restructure: q,k never materialized.
//   G_b = x_b^T x_b  [768][768]  (symmetric, split-K atomics)
//   P_b = G_b @ [Wq|Wk]          [768][1536], stored transposed PT [j][c]
//   S_h = Wq_h^T Pk_h, norms = rowdot(W, P)  -> softmax -> attn bf16 [64][96][96]
//   U = attn @ v ; out = U @ Wproj + b
// XOR chunk swizzle on all MFMA LDS tiles (slot (row,c) holds chunk c ^ (row&7)).

typedef __attribute__((ext_vector_type(8))) __bf16 bf16x8;
typedef __attribute__((ext_vector_type(4))) float f32x4;

__device__ __forceinline__ unsigned short f2b(float f) {
  uint32_t u = __float_as_uint(f);
  u += 0x7FFF + ((u >> 16) & 1);
  return (unsigned short)(u >> 16);
}
__device__ __forceinline__ float b2f(unsigned short h) {
  return __uint_as_float(((uint32_t)h) << 16);
}

__device__ __forceinline__ void gload16(const void* g, void* l) {
  __builtin_amdgcn_global_load_lds(
      (__attribute__((address_space(1))) void*)(uintptr_t)g,
      (__attribute__((address_space(3))) void*)(uintptr_t)l, 16, 0, 0);
}

__device__ __forceinline__ float dot8(uint4 a, uint4 b) {
  float s = 0.f;
  const uint32_t* pa = (const uint32_t*)&a;
  const uint32_t* pb = (const uint32_t*)&b;
#pragma unroll
  for (int i = 0; i < 4; i++) {
    s += b2f((unsigned short)(pa[i] & 0xffff)) * b2f((unsigned short)(pb[i] & 0xffff));
    s += b2f((unsigned short)(pa[i] >> 16)) * b2f((unsigned short)(pb[i] >> 16));
  }
  return s;
}

// ---------------- cvt_dual: x -> xb [n][c] and xT [b][c][n]; zero G ----------------
__global__ __launch_bounds__(256) void cvt_dual(const float* __restrict__ x,
                                                unsigned short* __restrict__ xb,
                                                unsigned short* __restrict__ xT,
                                                float* __restrict__ G) {
  int tid = threadIdx.x;
  int gid = (blockIdx.y * 512 + blockIdx.x) * 256 + tid;
  if (gid < 1179648) reinterpret_cast<float4*>(G)[gid] = make_float4(0.f, 0.f, 0.f, 0.f);
  __shared__ float tile[64][65];
  int n0 = blockIdx.x * 64, c0 = blockIdx.y * 64;
#pragma unroll
  for (int it = 0; it < 4; it++) {
    int slot = tid + it * 256;
    int row = slot >> 4, c16 = slot & 15;
    float4 v = *(const float4*)&x[(size_t)(n0 + row) * 768 + c0 + c16 * 4];
    tile[row][c16 * 4 + 0] = v.x; tile[row][c16 * 4 + 1] = v.y;
    tile[row][c16 * 4 + 2] = v.z; tile[row][c16 * 4 + 3] = v.w;
  }
  __syncthreads();
  int b = n0 >> 12, nl = n0 & 4095;
#pragma unroll
  for (int it = 0; it < 2; it++) {
    int slot = tid + it * 256;
    int row = slot >> 3, cg = slot & 7;
    unsigned short tmp[8];
#pragma unroll
    for (int j = 0; j < 8; j++) tmp[j] = f2b(tile[row][cg * 8 + j]);
    *(uint4*)&xb[(size_t)(n0 + row) * 768 + c0 + cg * 8] = *(const uint4*)tmp;
  }
#pragma unroll
  for (int it = 0; it < 2; it++) {
    int slot = tid + it * 256;
    int crow = slot >> 3, ng = slot & 7;
    unsigned short tmp[8];
#pragma unroll
    for (int j = 0; j < 8; j++) tmp[j] = f2b(tile[ng * 8 + j][crow]);
    *(uint4*)&xT[(size_t)b * 3145728 + (size_t)(c0 + crow) * 4096 + nl + ng * 8] =
        *(const uint4*)tmp;
  }
}

// ---------------- generic fp32 -> bf16 convert (grid-stride) ----------------
__global__ void cvt_bf16(const float* __restrict__ in, unsigned short* __restrict__ out, int n4) {
  int stride = gridDim.x * blockDim.x;
  for (int i = blockIdx.x * blockDim.x + threadIdx.x; i < n4; i += stride) {
    float4 v = reinterpret_cast<const float4*>(in)[i];
    ushort4 o;
    o.x = f2b(v.x); o.y = f2b(v.y); o.z = f2b(v.z); o.w = f2b(v.w);
    reinterpret_cast<ushort4*>(out)[i] = o;
  }
}

__global__ void cvt_transpose(const float* __restrict__ in, unsigned short* __restrict__ out,
                              int K, int NC) {
  __shared__ float tile[32][33];
  int bx = blockIdx.x, by = blockIdx.y;
  int tx = threadIdx.x & 31, ty = threadIdx.x >> 5;
  for (int r = ty; r < 32; r += 8)
    tile[r][tx] = in[(size_t)(by * 32 + r) * NC + bx * 32 + tx];
  __syncthreads();
  for (int r = ty; r < 32; r += 8)
    out[(size_t)(bx * 32 + r) * K + by * 32 + tx] = f2b(tile[tx][r]);
}

// ---------------- gemm_v: vT[bh][n][e] = x @ Wv ----------------
__global__ __launch_bounds__(256, 2) void gemm_v(
    const unsigned short* __restrict__ A, const unsigned short* __restrict__ Bt,
    unsigned short* __restrict__ vT) {
  __shared__ __align__(16) unsigned short lds[17408];
  int bj = blockIdx.x;                        // 0..5
  int bm = blockIdx.y;                        // 0..255
  int m0 = bm * 128, j0 = bj * 128;
  int tid = threadIdx.x;
  int wid = tid >> 6, lane = tid & 63;
  int wm = wid >> 1, wn = wid & 1;
  int quad = lane >> 4, l16 = lane & 15;
  int srow = lane >> 3, sch = lane & 7;
  int cmem = sch ^ srow;

  f32x4 acc[4][4];
  f32x4 z = {0.f, 0.f, 0.f, 0.f};
#pragma unroll
  for (int i = 0; i < 4; i++)
#pragma unroll
    for (int j = 0; j < 4; j++) acc[i][j] = z;

  const unsigned short* Ab = A + (size_t)m0 * 768;
  const unsigned short* Bb = Bt + (size_t)(1536 + j0) * 768;

  for (int k0 = 0; k0 < 768; k0 += 64) {
#pragma unroll
    for (int i = 0; i < 4; i++) {
      int ig = wid * 4 + i;
      int row = ig * 8 + srow;
      gload16(Ab + (size_t)row * 768 + k0 + cmem * 8, &lds[ig * 512]);
      gload16(Bb + (size_t)row * 768 + k0 + cmem * 8, &lds[8192 + ig * 512]);
    }
    __syncthreads();
#pragma unroll
    for (int kk = 0; kk < 2; kk++) {
      int cs = ((kk * 4 + quad) ^ (l16 & 7)) * 8;
      bf16x8 af[4], bfr[4];
#pragma unroll
      for (int mi = 0; mi < 4; mi++)
        af[mi] = *(const bf16x8*)&lds[(wm * 64 + mi * 16 + l16) * 64 + cs];
#pragma unroll
      for (int ni = 0; ni < 4; ni++)
        bfr[ni] = *(const bf16x8*)&lds[8192 + (wn * 64 + ni * 16 + l16) * 64 + cs];
#pragma unroll
      for (int mi = 0; mi < 4; mi++)
#pragma unroll
        for (int ni = 0; ni < 4; ni++)
          acc[mi][ni] = __builtin_amdgcn_mfma_f32_16x16x32_bf16(af[mi], bfr[ni], acc[mi][ni], 0, 0, 0);
    }
    __syncthreads();
  }

  int b = bm >> 5;
  int n0 = m0 & 4095;
  // bounce [n][c] padded 136
#pragma unroll
  for (int mi = 0; mi < 4; mi++)
#pragma unroll
    for (int ni = 0; ni < 4; ni++)
#pragma unroll
      for (int r = 0; r < 4; r++) {
        int m = wm * 64 + mi * 16 + quad * 4 + r;
        int cc = wn * 64 + ni * 16 + l16;
        lds[m * 136 + cc] = f2b(acc[mi][ni][r]);
      }
  __syncthreads();
#pragma unroll
  for (int it = 0; it < 8; it++) {
    int id = tid + it * 256;
    int mr = id >> 4, ch = id & 15;
    int cp = j0 + ch * 8;
    int hh = cp / 96, e = cp - hh * 96;
    size_t off = ((size_t)(b * 8 + hh) * 4096 + (n0 + mr)) * 96 + e;
    *(uint4*)&vT[off] = *(const uint4*)&lds[mr * 136 + ch * 8];
  }
}

// ---------------- gemm_G: G_b = x_b^T x_b (triangle tiles, split-K=4, atomics) ----------------
__global__ __launch_bounds__(256, 2) void gemm_G(const unsigned short* __restrict__ xT,
                                                 float* __restrict__ G) {
  __shared__ __align__(16) unsigned short lds[16384];
  int t = blockIdx.x;                       // 0..20 -> (ti, tj<=ti)
  int ti = 0;
  while (t >= ti + 1) { t -= ti + 1; ti++; }
  int tj = t;
  int z = blockIdx.y;                       // 0..31
  int b = z >> 2, ks = z & 3;
  int kbase = ks * 1024;
  int tid = threadIdx.x;
  int wid = tid >> 6, lane = tid & 63;
  int wm = wid >> 1, wn = wid & 1;
  int quad = lane >> 4, l16 = lane & 15;
  int srow = lane >> 3, sch = lane & 7;
  int cmem = sch ^ srow;

  f32x4 acc[4][4];
  f32x4 zz = {0.f, 0.f, 0.f, 0.f};
#pragma unroll
  for (int i = 0; i < 4; i++)
#pragma unroll
    for (int j = 0; j < 4; j++) acc[i][j] = zz;

  const unsigned short* Ab = xT + (size_t)b * 3145728 + (size_t)(ti * 128) * 4096 + kbase;
  const unsigned short* Bb = xT + (size_t)b * 3145728 + (size_t)(tj * 128) * 4096 + kbase;

  for (int k0 = 0; k0 < 1024; k0 += 64) {
#pragma unroll
    for (int i = 0; i < 4; i++) {
      int ig = wid * 4 + i;
      int row = ig * 8 + srow;
      gload16(Ab + (size_t)row * 4096 + k0 + cmem * 8, &lds[ig * 512]);
      gload16(Bb + (size_t)row * 4096 + k0 + cmem * 8, &lds[8192 + ig * 512]);
    }
    __syncthreads();
#pragma unroll
    for (int kk = 0; kk < 2; kk++) {
      int cs = ((kk * 4 + quad) ^ (l16 & 7)) * 8;
      bf16x8 af[4], bfr[4];
#pragma unroll
      for (int mi = 0; mi < 4; mi++)
        af[mi] = *(const bf16x8*)&lds[(wm * 64 + mi * 16 + l16) * 64 + cs];
#pragma unroll
      for (int ni = 0; ni < 4; ni++)
        bfr[ni] = *(const bf16x8*)&lds[8192 + (wn * 64 + ni * 16 + l16) * 64 + cs];
#pragma unroll
      for (int mi = 0; mi < 4; mi++)
#pragma unroll
        for (int ni = 0; ni < 4; ni++)
          acc[mi][ni] = __builtin_amdgcn_mfma_f32_16x16x32_bf16(af[mi], bfr[ni], acc[mi][ni], 0, 0, 0);
    }
    __syncthreads();
  }

  float* Gb = G + (size_t)b * 589824;
  bool mirror = (ti != tj);
#pragma unroll
  for (int mi = 0; mi < 4; mi++)
#pragma unroll
    for (int ni = 0; ni < 4; ni++)
#pragma unroll
      for (int r = 0; r < 4; r++) {
        int gi = ti * 128 + wm * 64 + mi * 16 + quad * 4 + r;
        int gj = tj * 128 + wn * 64 + ni * 16 + l16;
        float v = acc[mi][ni][r];
        atomicAdd(&Gb[(size_t)gi * 768 + gj], v);
        if (mirror) atomicAdd(&Gb[(size_t)gj * 768 + gi], v);
      }
}

// ---------------- S1: PT[b][j][c] = (G_b @ Wqk)^T ----------------
__global__ __launch_bounds__(256, 2) void gemm_P(
    const unsigned short* __restrict__ Gbf, const unsigned short* __restrict__ Wt,
    unsigned short* __restrict__ PT) {
  __shared__ __align__(16) unsigned short lds[17408];
  int bj = blockIdx.x;                     // 0..11 (j tiles over 1536)
  int bi = blockIdx.y;                     // 0..5  (c tiles over 768)
  int b = blockIdx.z;                      // 0..7
  int j0 = bj * 128, ci0 = bi * 128;
  int tid = threadIdx.x;
  int wid = tid >> 6, lane = tid & 63;
  int wm = wid >> 1, wn = wid & 1;
  int quad = lane >> 4, l16 = lane & 15;
  int srow = lane >> 3, sch = lane & 7;
  int cmem = sch ^ srow;

  f32x4 acc[4][4];
  f32x4 z = {0.f, 0.f, 0.f, 0.f};
#pragma unroll
  for (int i = 0; i < 4; i++)
#pragma unroll
    for (int j = 0; j < 4; j++) acc[i][j] = z;

  const unsigned short* Ab = Gbf + (size_t)b * 589824 + (size_t)ci0 * 768;
  const unsigned short* Bb = Wt + (size_t)j0 * 768;

  for (int k0 = 0; k0 < 768; k0 += 64) {
#pragma unroll
    for (int i = 0; i < 4; i++) {
      int ig = wid * 4 + i;
      int row = ig * 8 + srow;
      gload16(Ab + (size_t)row * 768 + k0 + cmem * 8, &lds[ig * 512]);
      gload16(Bb + (size_t)row * 768 + k0 + cmem * 8, &lds[8192 + ig * 512]);
    }
    __syncthreads();
#pragma unroll
    for (int kk = 0; kk < 2; kk++) {
      int cs = ((kk * 4 + quad) ^ (l16 & 7)) * 8;
      bf16x8 af[4], bfr[4];
#pragma unroll
      for (int mi = 0; mi < 4; mi++)
        af[mi] = *(const bf16x8*)&lds[(wm * 64 + mi * 16 + l16) * 64 + cs];
#pragma unroll
      for (int ni = 0; ni < 4; ni++)
        bfr[ni] = *(const bf16x8*)&lds[8192 + (wn * 64 + ni * 16 + l16) * 64 + cs];
#pragma unroll
      for (int mi = 0; mi < 4; mi++)
#pragma unroll
        for (int ni = 0; ni < 4; ni++)
          acc[mi][ni] = __builtin_amdgcn_mfma_f32_16x16x32_bf16(af[mi], bfr[ni], acc[mi][ni], 0, 0, 0);
    }
    __syncthreads();
  }

  // bounce transposed: [j][c]
#pragma unroll
  for (int mi = 0; mi < 4; mi++)
#pragma unroll
    for (int ni = 0; ni < 4; ni++)
#pragma unroll
      for (int r = 0; r < 4; r++) {
        int m = wm * 64 + mi * 16 + quad * 4 + r;    // c within tile
        int cc = wn * 64 + ni * 16 + l16;            // j within tile
        lds[cc * 136 + m] = f2b(acc[mi][ni][r]);
      }
  __syncthreads();
#pragma unroll
  for (int it = 0; it < 8; it++) {
    int id = tid + it * 256;
    int jr = id >> 4, mc = id & 15;
    size_t off = ((size_t)(b * 1536 + j0 + jr)) * 768 + ci0 + mc * 8;
    *(uint4*)&PT[off] = *(const uint4*)&lds[jr * 136 + mc * 8];
  }
}

// ---------------- S2: S = Wq^T Pk, norms, softmax -> attn bf16 [bh][96][96] ----------------
__global__ __launch_bounds__(256, 2) void attn_softmax(
    const unsigned short* __restrict__ Wt, const unsigned short* __restrict__ PT,
    const float* __restrict__ temp, unsigned short* __restrict__ attnP) {
  __shared__ __align__(16) char smem[39168];
  unsigned short* stg = (unsigned short*)smem;      // staging 2 x 96x64 = 24576 B
  float* Sf = (float*)smem;                         // 96 x 100 fp32 = 38400 B (after MFMA)
  float* ninv = (float*)(smem + 38400);             // 192 floats
  int bh = blockIdx.x;
  int b = bh >> 3, h = bh & 7;
  int tid = threadIdx.x, wid = tid >> 6, lane = tid & 63;
  int wm = wid >> 1, wn = wid & 1, quad = lane >> 4, l16 = lane & 15;
  int srow = lane >> 3, sch = lane & 7;
  int cmem = sch ^ srow;

  const unsigned short* Arow = Wt + (size_t)(h * 96) * 768;                       // Wq rows
  const unsigned short* Brow = PT + (size_t)(b * 1536 + 768 + h * 96) * 768;      // Pk rows

  f32x4 acc[3][3];
  f32x4 z = {0.f, 0.f, 0.f, 0.f};
#pragma unroll
  for (int i = 0; i < 3; i++)
#pragma unroll
    for (int j = 0; j < 3; j++) acc[i][j] = z;

  for (int k0 = 0; k0 < 768; k0 += 64) {
#pragma unroll
    for (int i = 0; i < 3; i++) {
      int ig = wid * 3 + i;                 // 0..11, 8 rows each = 96
      int row = ig * 8 + srow;
      gload16(Arow + (size_t)row * 768 + k0 + cmem * 8, &stg[ig * 512]);
      gload16(Brow + (size_t)row * 768 + k0 + cmem * 8, &stg[6144 + ig * 512]);
    }
    __syncthreads();
#pragma unroll
    for (int kk = 0; kk < 2; kk++) {
      int cs = ((kk * 4 + quad) ^ (l16 & 7)) * 8;
      bf16x8 af[3], bfr[3];
#pragma unroll
      for (int mi = 0; mi < 3; mi++)
        af[mi] = *(const bf16x8*)&stg[(wm * 48 + mi * 16 + l16) * 64 + cs];
#pragma unroll
      for (int ni = 0; ni < 3; ni++)
        bfr[ni] = *(const bf16x8*)&stg[6144 + (wn * 48 + ni * 16 + l16) * 64 + cs];
#pragma unroll
      for (int mi = 0; mi < 3; mi++)
#pragma unroll
        for (int ni = 0; ni < 3; ni++)
          acc[mi][ni] = __builtin_amdgcn_mfma_f32_16x16x32_bf16(af[mi], bfr[ni], acc[mi][ni], 0, 0, 0);
    }
    __syncthreads();
  }

  // bounce raw S (fp32) into Sf
#pragma unroll
  for (int mi = 0; mi < 3; mi++)
#pragma unroll
    for (int ni = 0; ni < 3; ni++)
#pragma unroll
      for (int r = 0; r < 4; r++)
        Sf[(wm * 48 + mi * 16 + quad * 4 + r) * 100 + wn * 48 + ni * 16 + l16] = acc[mi][ni][r];

  // norms: ninv[0..95]=1/||q_d||, ninv[96..191]=1/||k_e|| via rowdot(W, P)
  if (tid < 192) {
    int qsel = tid < 96 ? 0 : 1;
    int d = tid - qsel * 96;
    const unsigned short* wrow = Wt + (size_t)(qsel * 768 + h * 96 + d) * 768;
    const unsigned short* prow = PT + (size_t)(b * 1536 + qsel * 768 + h * 96 + d) * 768;
    float s = 0.f;
#pragma unroll 4
    for (int c8 = 0; c8 < 96; c8++)
      s += dot8(*(const uint4*)&wrow[c8 * 8], *(const uint4*)&prow[c8 * 8]);
    ninv[tid] = 1.0f / fmaxf(sqrtf(fmaxf(s, 0.f)), 1e-12f);
  }
  __syncthreads();

  if (tid < 96) {
    int d = tid;
    float iq = ninv[d] * temp[h];
    float mx = -1e30f;
    for (int e = 0; e < 96; e++) mx = fmaxf(mx, Sf[d * 100 + e] * iq * ninv[96 + e]);
    float sum = 0.f;
    for (int e = 0; e < 96; e++) sum += __expf(Sf[d * 100 + e] * iq * ninv[96 + e] - mx);
    float inv = 1.0f / sum;
    for (int e = 0; e < 96; e++)
      Sf[d * 100 + e] = __expf(Sf[d * 100 + e] * iq * ninv[96 + e] - mx) * inv;
  }
  __syncthreads();

  for (int idx = tid; idx < 1152; idx += 256) {
    int row = idx / 12, ch = idx - row * 12;
    unsigned short tmp[8];
#pragma unroll
    for (int j = 0; j < 8; j++) tmp[j] = f2b(Sf[row * 100 + ch * 8 + j]);
    *(uint4*)&attnP[(size_t)bh * 9216 + row * 96 + ch * 8] = *(const uint4*)tmp;
  }
}

// ---------------- attn_v: U[b][n][c] = attn @ v ----------------
__global__ __launch_bounds__(256, 2) void attn_v(
    const unsigned short* __restrict__ attnP, const unsigned short* __restrict__ vT,
    unsigned short* __restrict__ U) {
  // attn [96][104]@0 (9984 elems), vs [128][13 chunks][8]@9984 (13312 elems)
  __shared__ __align__(16) unsigned short lds[23296];
  int blk = blockIdx.x;
  int bh = blk >> 5, nc = blk & 31;
  int b = bh >> 3, h = bh & 7;
  int n0 = nc * 128;
  int tid = threadIdx.x, wid = tid >> 6, lane = tid & 63;
  int wm = wid >> 1, wn = wid & 1, quad = lane >> 4, l16 = lane & 15;

  // stage v [128 n][96 e] -> 13-chunk padded rows (208B, 2-way banks)
  const unsigned short* vb = vT + (size_t)bh * 4096 * 96 + (size_t)n0 * 96;
#pragma unroll
  for (int i = 0; i < 7; i++) {
    int ig = wid + i * 4;
    if (ig < 26) {
      int id = ig * 64 + lane;
      int row = id / 13;
      int ch = id - row * 13;
      if (ch > 11) ch = 11;
      gload16(vb + (size_t)row * 96 + ch * 8, &lds[9984 + ig * 512]);
    }
  }
  // stage attn [96][96] -> pitch 104
  for (int idx = tid; idx < 1152; idx += 256) {
    int row = idx / 12, ch = idx - row * 12;
    *(uint4*)&lds[row * 104 + ch * 8] = *(const uint4*)&attnP[(size_t)bh * 9216 + row * 96 + ch * 8];
  }
  __syncthreads();

  f32x4 acc[3][4];
  f32x4 z = {0.f, 0.f, 0.f, 0.f};
#pragma unroll
  for (int i = 0; i < 3; i++)
#pragma unroll
    for (int j = 0; j < 4; j++) acc[i][j] = z;
#pragma unroll
  for (int et = 0; et < 3; et++) {
    bf16x8 af[3], bfr[4];
#pragma unroll
    for (int mi = 0; mi < 3; mi++)
      af[mi] = *(const bf16x8*)&lds[(wm * 48 + mi * 16 + l16) * 104 + (et * 4 + quad) * 8];
#pragma unroll
    for (int ni = 0; ni < 4; ni++)
      bfr[ni] = *(const bf16x8*)&lds[9984 + (wn * 64 + ni * 16 + l16) * 104 + (et * 4 + quad) * 8];
#pragma unroll
    for (int mi = 0; mi < 3; mi++)
#pragma unroll
      for (int ni = 0; ni < 4; ni++)
        acc[mi][ni] = __builtin_amdgcn_mfma_f32_16x16x32_bf16(af[mi], bfr[ni], acc[mi][ni], 0, 0, 0);
  }
  __syncthreads();

  // bounce [128 n][104] then coalesced U writes
#pragma unroll
  for (int mi = 0; mi < 3; mi++)
#pragma unroll
    for (int ni = 0; ni < 4; ni++)
#pragma unroll
      for (int r = 0; r < 4; r++) {
        int d = wm * 48 + mi * 16 + quad * 4 + r;
        int n = wn * 64 + ni * 16 + l16;
        lds[n * 104 + d] = f2b(acc[mi][ni][r]);
      }
  __syncthreads();
#pragma unroll
  for (int it = 0; it < 6; it++) {
    int id = tid + it * 256;
    int nr = id / 12, ch = id - nr * 12;
    *(uint4*)&U[((size_t)(b * 4096 + n0 + nr)) * 768 + h * 96 + ch * 8] =
        *(const uint4*)&lds[nr * 104 + ch * 8];
  }
}

// ---------------- gemm_out: y = U @ Wproj + bproj ----------------
__global__ __launch_bounds__(256, 2) void gemm_out(
    const unsigned short* __restrict__ A, const unsigned short* __restrict__ Bt,
    const float* __restrict__ bias, float* __restrict__ out) {
  __shared__ __align__(16) unsigned short lds[16384];
  int bj = blockIdx.x;                      // 0..5
  int bm = blockIdx.y;                      // 0..255
  int m0 = bm * 128, j0 = bj * 128;
  int tid = threadIdx.x;
  int wid = tid >> 6, lane = tid & 63;
  int wm = wid >> 1, wn = wid & 1;
  int quad = lane >> 4, l16 = lane & 15;
  int srow = lane >> 3, sch = lane & 7;
  int cmem = sch ^ srow;

  f32x4 acc[4][4];
  f32x4 z = {0.f, 0.f, 0.f, 0.f};
#pragma unroll
  for (int i = 0; i < 4; i++)
#pragma unroll
    for (int j = 0; j < 4; j++) acc[i][j] = z;

  const unsigned short* Ab = A + (size_t)m0 * 768;
  const unsigned short* Bb = Bt + (size_t)j0 * 768;

  for (int k0 = 0; k0 < 768; k0 += 64) {
#pragma unroll
    for (int i = 0; i < 4; i++) {
      int ig = wid * 4 + i;
      int row = ig * 8 + srow;
      gload16(Ab + (size_t)row * 768 + k0 + cmem * 8, &lds[ig * 512]);
      gload16(Bb + (size_t)row * 768 + k0 + cmem * 8, &lds[8192 + ig * 512]);
    }
    __syncthreads();
#pragma unroll
    for (int kk = 0; kk < 2; kk++) {
      int cs = ((kk * 4 + quad) ^ (l16 & 7)) * 8;
      bf16x8 af[4], bfr[4];
#pragma unroll
      for (int mi = 0; mi < 4; mi++)
        af[mi] = *(const bf16x8*)&lds[(wm * 64 + mi * 16 + l16) * 64 + cs];
#pragma unroll
      for (int ni = 0; ni < 4; ni++)
        bfr[ni] = *(const bf16x8*)&lds[8192 + (wn * 64 + ni * 16 + l16) * 64 + cs];
#pragma unroll
      for (int mi = 0; mi < 4; mi++)
#pragma unroll
        for (int ni = 0; ni < 4; ni++)
          acc[mi][ni] = __builtin_amdgcn_mfma_f32_16x16x32_bf16(af[mi], bfr[ni], acc[mi][ni], 0, 0, 0);
    }
    __syncthreads();
  }
#pragma unroll
  for (int ni = 0; ni < 4; ni++) {
    int ccol = j0 + wn * 64 + ni * 16 + l16;
    float bv = bias[ccol];
#pragma unroll
    for (int mi = 0; mi < 4; mi++)
#pragma unroll
      for (int r = 0; r < 4; r++)
        out[(size_t)(m0 + wm * 64 + mi * 16 + quad * 4 + r) * 768 + ccol] = acc[mi][ni][r] + bv;
  }
}

// ---------------- host ----------------
extern "C" void kernel_launch(void* const* d_in, const int* in_sizes, int n_in,
                              void* d_out, int out_size, void* d_ws, size_t ws_size,
                              hipStream_t stream) {
  const float* x = (const float*)d_in[0];
  const float* Wqkv = (const float*)d_in[1];
  const float* temp = (const float*)d_in[2];
  const float* Wproj = (const float*)d_in[3];
  const float* bproj = (const float*)d_in[4];
  float* out = (float*)d_out;
  char* ws = (char*)d_ws;

  unsigned short* xb     = (unsigned short*)(ws);                 // 50331648 B
  unsigned short* WqkvT  = (unsigned short*)(ws + 50331648);      // 3538944
  unsigned short* WprojT = (unsigned short*)(ws + 53870592);      // 1179648
  unsigned short* xT     = (unsigned short*)(ws + 55050240);      // 50331648
  unsigned short* vT     = (unsigned short*)(ws + 105381888);     // 50331648
  unsigned short* U      = (unsigned short*)(ws + 155713536);     // 50331648
  float* G               = (float*)(ws + 206045184);              // 18874368
  unsigned short* Gbf    = (unsigned short*)(ws + 224919552);     // 9437184
  unsigned short* PT     = (unsigned short*)(ws + 234356736);     // 18874368
  unsigned short* attnP  = (unsigned short*)(ws + 253231104);     // 1179648

  cvt_dual<<<dim3(512, 12), dim3(256), 0, stream>>>(x, xb, xT, G);
  cvt_transpose<<<dim3(72, 24), dim3(256), 0, stream>>>(Wqkv, WqkvT, 768, 2304);
  cvt_transpose<<<dim3(24, 24), dim3(256), 0, stream>>>(Wproj, WprojT, 768, 768);
  gemm_v<<<dim3(6, 256), dim3(256), 0, stream>>>(xb, WqkvT, vT);
  gemm_G<<<dim3(21, 32), dim3(256), 0, stream>>>(xT, G);
  cvt_bf16<<<dim3(2048), dim3(256), 0, stream>>>(G, Gbf, 1179648);
  gemm_P<<<dim3(12, 6, 8), dim3(256), 0, stream>>>(Gbf, WqkvT, PT);
  attn_softmax<<<dim3(64), dim3(256), 0, stream>>>(WqkvT, PT, temp, attnP);
  attn_v<<<dim3(2048), dim3(256), 0, stream>>>(attnP, vT, U);
  gemm_out<<<dim3(6, 256), dim3(256), 0, stream>>>(U, WprojT, bproj, out);
}